// Round 5
// baseline (251.676 us; speedup 1.0000x reference)
//
#include <hip/hip_runtime.h>
#include <hip/hip_bf16.h>
#include <math.h>

#define N_CELLS 65536
#define D_DIM   128
#define K_PROTO 2048

typedef __attribute__((ext_vector_type(8))) short bf16x8;
typedef __attribute__((ext_vector_type(4))) float f32x4;

// ---- order-preserving float<->uint mapping for atomic min/max ----
__device__ __forceinline__ unsigned int map_f2u(float f) {
  unsigned int u = __float_as_uint(f);
  return (u & 0x80000000u) ? ~u : (u | 0x80000000u);
}
__device__ __forceinline__ float unmap_u2f(unsigned int u) {
  unsigned int b = (u & 0x80000000u) ? (u ^ 0x80000000u) : ~u;
  return __uint_as_float(b);
}

// RTN-even float -> bf16 bit pattern
__device__ __forceinline__ unsigned int f2bf(float f) {
  unsigned int u = __float_as_uint(f);
  return ((u + 0x7FFFu + ((u >> 16) & 1u)) >> 16) & 0xFFFFu;
}

// ---- K1: row-normalize x -> z (NT float4 out) + zb (packed bf16) + rowmin init ----
__global__ __launch_bounds__(256) void normalize_k(
    const float* __restrict__ x, float* __restrict__ z,
    unsigned int* __restrict__ zb, unsigned int* __restrict__ rowmin_u) {
  int tid = threadIdx.x;
  int sub = tid & 31;                       // lane within half-wave = col group
  int row = blockIdx.x * 8 + (tid >> 5);    // one row per 32 lanes
  const f32x4* xr = (const f32x4*)(x + (size_t)row * D_DIM);
  f32x4 v = xr[sub];
  float s = v.x * v.x + v.y * v.y + v.z * v.z + v.w * v.w;
  #pragma unroll
  for (int off = 1; off < 32; off <<= 1) s += __shfl_xor(s, off, 64);
  float inv = 1.0f / fmaxf(sqrtf(s), 1e-12f);
  f32x4 zv = v * inv;
  __builtin_nontemporal_store(zv, (f32x4*)(z + (size_t)row * D_DIM) + sub);
  unsigned int lo = (f2bf(zv.y) << 16) | f2bf(zv.x);
  unsigned int h2 = (f2bf(zv.w) << 16) | f2bf(zv.z);
  unsigned long long pk = ((unsigned long long)h2 << 32) | lo;
  *((unsigned long long*)(zb + (size_t)row * (D_DIM / 2)) + sub) = pk;
  if (sub == 0) rowmin_u[row] = 0xFFFFFFFFu;  // min identity (mapped order)
}

// ---- K2: W -> bf16 + ww norms + colmax init; block 0 writes cvae ----
__global__ __launch_bounds__(256) void wprep_k(
    const float* __restrict__ W, unsigned int* __restrict__ wb,
    float* __restrict__ ww, unsigned int* __restrict__ colmax_u,
    const float* __restrict__ recon, const float* __restrict__ kl,
    const float* __restrict__ mmd, float* __restrict__ scal) {
  if (blockIdx.x == 0 && threadIdx.x == 0) {
    scal[0] = recon[0] + 0.5f * kl[0] + mmd[0];  // cvae_loss
  }
  int tid = threadIdx.x;
  int sub = tid & 31;
  int row = blockIdx.x * 8 + (tid >> 5);
  const f32x4* wr = (const f32x4*)(W + (size_t)row * D_DIM);
  f32x4 v = wr[sub];
  float s = v.x * v.x + v.y * v.y + v.z * v.z + v.w * v.w;
  #pragma unroll
  for (int off = 1; off < 32; off <<= 1) s += __shfl_xor(s, off, 64);
  if (sub == 0) {
    ww[row] = s;
    colmax_u[row] = 0u;  // max identity (mapped order)
  }
  unsigned int lo = (f2bf(v.y) << 16) | f2bf(v.x);
  unsigned int h2 = (f2bf(v.w) << 16) | f2bf(v.z);
  unsigned long long pk = ((unsigned long long)h2 << 32) | lo;
  *((unsigned long long*)(wb + (size_t)row * (D_DIM / 2)) + sub) = pk;
}

// ---- K3: LDS-free GEMM, swapped operands -> dwordx4 logits stores ----
__global__ __launch_bounds__(256) void gemm_k(
    const unsigned short* __restrict__ zb, const unsigned short* __restrict__ wb,
    const float* __restrict__ ww, float* __restrict__ logits,
    unsigned int* __restrict__ rowmin_u, unsigned int* __restrict__ colmax_u) {
  // XCD-chunked bijective swizzle: 8192 blocks = 8 XCDs x 1024
  int bid = blockIdx.x;
  int swz = (bid & 7) * 1024 + (bid >> 3);
  int nt  = swz & 15;   // 16 col tiles (protos)
  int mt  = swz >> 4;   // 512 row tiles (cells)

  int tid  = threadIdx.x;
  int lane = tid & 63;
  int wid  = tid >> 6;
  int wrow = (wid >> 1) * 64;   // cell offset within tile
  int wcol = (wid & 1) * 64;    // proto offset within tile
  int l15  = lane & 15;
  int hi   = lane >> 4;

  // fragment base addresses: row-major bf16, 256 B per row
  const char* Abase = (const char*)zb + ((size_t)(mt * 128 + wrow + l15) * 256 + hi * 16);
  const char* Bbase = (const char*)wb + ((size_t)(nt * 128 + wcol + l15) * 256 + hi * 16);

  f32x4 acc[4][4];
  #pragma unroll
  for (int i = 0; i < 4; ++i)
    #pragma unroll
    for (int j = 0; j < 4; ++j)
      acc[i][j] = f32x4{0.f, 0.f, 0.f, 0.f};

  #pragma unroll
  for (int kk = 0; kk < 4; ++kk) {
    bf16x8 a[4], b[4];
    #pragma unroll
    for (int i = 0; i < 4; ++i) a[i] = *(const bf16x8*)(Abase + i * 4096 + kk * 64);
    #pragma unroll
    for (int j = 0; j < 4; ++j) b[j] = *(const bf16x8*)(Bbase + j * 4096 + kk * 64);
    // SWAPPED: M-operand = protos, N-operand = cells  =>  C/D reg axis = protos
    #pragma unroll
    for (int i = 0; i < 4; ++i)
      #pragma unroll
      for (int j = 0; j < 4; ++j)
        acc[i][j] = __builtin_amdgcn_mfma_f32_16x16x32_bf16(b[j], a[i], acc[i][j], 0, 0, 0);
  }

  // lane (hi,l15), acc[i][j][r]: cell = growbase + i*16 + l15
  //                              proto = gcolbase + j*16 + hi*4 + r
  size_t growbase = (size_t)mt * 128 + wrow;
  int    gcolbase = nt * 128 + wcol;

  f32x4 wwj[4];
  #pragma unroll
  for (int j = 0; j < 4; ++j)
    wwj[j] = *(const f32x4*)(ww + gcolbase + j * 16 + hi * 4);

  // store logits (plain dwordx4, L2-allocating) + rowmin(ww - 2L) tracking
  #pragma unroll
  for (int i = 0; i < 4; ++i) {
    size_t row = growbase + (size_t)(i * 16 + l15);
    float* lp = logits + row * K_PROTO + gcolbase + hi * 4;
    float vmin = 1e30f;
    #pragma unroll
    for (int j = 0; j < 4; ++j) {
      f32x4 c = acc[i][j];
      *(f32x4*)(lp + j * 16) = c;
      #pragma unroll
      for (int r = 0; r < 4; ++r) vmin = fminf(vmin, wwj[j][r] - 2.0f * c[r]);
    }
    vmin = fminf(vmin, __shfl_xor(vmin, 16, 64));
    vmin = fminf(vmin, __shfl_xor(vmin, 32, 64));
    if (hi == 0) atomicMin(&rowmin_u[row], map_f2u(vmin));
  }

  // colmax(L) per proto: reduce over cells (i regs + l15 lanes)
  #pragma unroll
  for (int j = 0; j < 4; ++j) {
    f32x4 m = acc[0][j];
    #pragma unroll
    for (int i = 1; i < 4; ++i)
      #pragma unroll
      for (int r = 0; r < 4; ++r) m[r] = fmaxf(m[r], acc[i][j][r]);
    #pragma unroll
    for (int s2 = 1; s2 < 16; s2 <<= 1)
      #pragma unroll
      for (int r = 0; r < 4; ++r) m[r] = fmaxf(m[r], __shfl_xor(m[r], s2, 64));
    if (l15 == 0) {
      #pragma unroll
      for (int r = 0; r < 4; ++r)
        atomicMax(&colmax_u[gcolbase + j * 16 + hi * 4 + r], map_f2u(m[r]));
    }
  }
}

// ---- K4: propagation = mean_n sqrt(max(1 + rowmin, 0)) ----
__global__ __launch_bounds__(1024) void prop_k(
    const unsigned int* __restrict__ rowmin_u, float* __restrict__ out) {
  __shared__ float sbuf[16];
  const uint4* p = (const uint4*)rowmin_u;  // 16384 uint4
  float s = 0.f;
  #pragma unroll
  for (int k = 0; k < 16; ++k) {
    uint4 u = p[threadIdx.x + 1024 * k];
    s += sqrtf(fmaxf(1.0f + unmap_u2f(u.x), 0.0f));
    s += sqrtf(fmaxf(1.0f + unmap_u2f(u.y), 0.0f));
    s += sqrtf(fmaxf(1.0f + unmap_u2f(u.z), 0.0f));
    s += sqrtf(fmaxf(1.0f + unmap_u2f(u.w), 0.0f));
  }
  #pragma unroll
  for (int off = 1; off < 64; off <<= 1) s += __shfl_xor(s, off, 64);
  int wid = threadIdx.x >> 6, lane = threadIdx.x & 63;
  if (lane == 0) sbuf[wid] = s;
  __syncthreads();
  if (threadIdx.x == 0) {
    float t = 0.f;
    #pragma unroll
    for (int w = 0; w < 16; ++w) t += sbuf[w];
    out[0] = t * (1.0f / N_CELLS);
  }
}

// ---- K5: emb_similarity = mean_k sqrt(max(1 + ww[k] - 2*colmax[k], 0)) ----
__global__ __launch_bounds__(1024) void emb_k(
    const unsigned int* __restrict__ colmax_u, const float* __restrict__ ww,
    float* __restrict__ out) {
  __shared__ float sbuf[16];
  float s = 0.f;
  for (int idx = threadIdx.x; idx < K_PROTO; idx += 1024)
    s += sqrtf(fmaxf(1.0f + ww[idx] - 2.0f * unmap_u2f(colmax_u[idx]), 0.0f));
  #pragma unroll
  for (int off = 1; off < 64; off <<= 1) s += __shfl_xor(s, off, 64);
  int wid = threadIdx.x >> 6, lane = threadIdx.x & 63;
  if (lane == 0) sbuf[wid] = s;
  __syncthreads();
  if (threadIdx.x == 0) {
    float t = 0.f;
    #pragma unroll
    for (int w = 0; w < 16; ++w) t += sbuf[w];
    out[0] = t * (1.0f / K_PROTO);
  }
}

extern "C" void kernel_launch(void* const* d_in, const int* in_sizes, int n_in,
                              void* d_out, int out_size, void* d_ws, size_t ws_size,
                              hipStream_t stream) {
  const float* x     = (const float*)d_in[0];
  const float* W     = (const float*)d_in[1];
  const float* recon = (const float*)d_in[2];
  const float* kl    = (const float*)d_in[3];
  const float* mmd   = (const float*)d_in[4];

  float* out    = (float*)d_out;
  float* z      = out;
  float* logits = out + (size_t)N_CELLS * D_DIM;
  float* scal   = logits + (size_t)N_CELLS * K_PROTO;  // [cvae, prop, emb]

  char* ws = (char*)d_ws;
  unsigned int* zb = (unsigned int*)ws;                     // 16 MiB packed bf16
  size_t off = (size_t)N_CELLS * D_DIM * 2;
  unsigned int* wb = (unsigned int*)(ws + off);             // 0.5 MiB
  off += (size_t)K_PROTO * D_DIM * 2;
  float* ww = (float*)(ws + off);                           // 8 KiB
  off += (size_t)K_PROTO * 4;
  unsigned int* rowmin_u = (unsigned int*)(ws + off);       // 256 KiB
  off += (size_t)N_CELLS * 4;
  unsigned int* colmax_u = (unsigned int*)(ws + off);       // 8 KiB

  normalize_k<<<N_CELLS / 8, 256, 0, stream>>>(x, z, zb, rowmin_u);
  wprep_k<<<K_PROTO / 8, 256, 0, stream>>>(W, wb, ww, colmax_u, recon, kl, mmd, scal);
  gemm_k<<<(N_CELLS / 128) * (K_PROTO / 128), 256, 0, stream>>>(
      (const unsigned short*)zb, (const unsigned short*)wb, ww, logits,
      rowmin_u, colmax_u);
  prop_k<<<1, 1024, 0, stream>>>(rowmin_u, scal + 1);
  emb_k<<<1, 1024, 0, stream>>>(colmax_u, ww, scal + 2);
}

// Round 6
// 242.996 us; speedup vs baseline: 1.0357x; 1.0357x over previous
//
#include <hip/hip_runtime.h>
#include <hip/hip_bf16.h>
#include <math.h>

#define N_CELLS 65536
#define D_DIM   128
#define K_PROTO 2048

typedef __attribute__((ext_vector_type(8))) short bf16x8;
typedef __attribute__((ext_vector_type(4))) float f32x4;

// ---- order-preserving float<->uint mapping for atomic min/max ----
__device__ __forceinline__ unsigned int map_f2u(float f) {
  unsigned int u = __float_as_uint(f);
  return (u & 0x80000000u) ? ~u : (u | 0x80000000u);
}
__device__ __forceinline__ float unmap_u2f(unsigned int u) {
  unsigned int b = (u & 0x80000000u) ? (u ^ 0x80000000u) : ~u;
  return __uint_as_float(b);
}

// RTN-even float -> bf16 bit pattern
__device__ __forceinline__ unsigned int f2bf(float f) {
  unsigned int u = __float_as_uint(f);
  return ((u + 0x7FFFu + ((u >> 16) & 1u)) >> 16) & 0xFFFFu;
}

// ---- K1: row-normalize x -> z (NT float4 out) + zb (packed bf16) + rowmin init ----
__global__ __launch_bounds__(256) void normalize_k(
    const float* __restrict__ x, float* __restrict__ z,
    unsigned int* __restrict__ zb, unsigned int* __restrict__ rowmin_u) {
  int tid = threadIdx.x;
  int sub = tid & 31;                       // lane within half-wave = col group
  int row = blockIdx.x * 8 + (tid >> 5);    // one row per 32 lanes
  const f32x4* xr = (const f32x4*)(x + (size_t)row * D_DIM);
  f32x4 v = xr[sub];
  float s = v.x * v.x + v.y * v.y + v.z * v.z + v.w * v.w;
  #pragma unroll
  for (int off = 1; off < 32; off <<= 1) s += __shfl_xor(s, off, 64);
  float inv = 1.0f / fmaxf(sqrtf(s), 1e-12f);
  f32x4 zv = v * inv;
  __builtin_nontemporal_store(zv, (f32x4*)(z + (size_t)row * D_DIM) + sub);
  unsigned int lo = (f2bf(zv.y) << 16) | f2bf(zv.x);
  unsigned int h2 = (f2bf(zv.w) << 16) | f2bf(zv.z);
  unsigned long long pk = ((unsigned long long)h2 << 32) | lo;
  *((unsigned long long*)(zb + (size_t)row * (D_DIM / 2)) + sub) = pk;
  if (sub == 0) rowmin_u[row] = 0xFFFFFFFFu;  // min identity (mapped order)
}

// ---- K2: W -> bf16 + ww norms + colmax init; block 0 writes cvae ----
__global__ __launch_bounds__(256) void wprep_k(
    const float* __restrict__ W, unsigned int* __restrict__ wb,
    float* __restrict__ ww, unsigned int* __restrict__ colmax_u,
    const float* __restrict__ recon, const float* __restrict__ kl,
    const float* __restrict__ mmd, float* __restrict__ scal) {
  if (blockIdx.x == 0 && threadIdx.x == 0) {
    scal[0] = recon[0] + 0.5f * kl[0] + mmd[0];  // cvae_loss
  }
  int tid = threadIdx.x;
  int sub = tid & 31;
  int row = blockIdx.x * 8 + (tid >> 5);
  const f32x4* wr = (const f32x4*)(W + (size_t)row * D_DIM);
  f32x4 v = wr[sub];
  float s = v.x * v.x + v.y * v.y + v.z * v.z + v.w * v.w;
  #pragma unroll
  for (int off = 1; off < 32; off <<= 1) s += __shfl_xor(s, off, 64);
  if (sub == 0) {
    ww[row] = s;
    colmax_u[row] = 0u;  // max identity (mapped order)
  }
  unsigned int lo = (f2bf(v.y) << 16) | f2bf(v.x);
  unsigned int h2 = (f2bf(v.w) << 16) | f2bf(v.z);
  unsigned long long pk = ((unsigned long long)h2 << 32) | lo;
  *((unsigned long long*)(wb + (size_t)row * (D_DIM / 2)) + sub) = pk;
}

// ---- K3: LDS-free mainloop GEMM + LDS-transposed contiguous store epilogue ----
__global__ __launch_bounds__(256) void gemm_k(
    const unsigned short* __restrict__ zb, const unsigned short* __restrict__ wb,
    const float* __restrict__ ww, float* __restrict__ logits,
    unsigned int* __restrict__ rowmin_u, unsigned int* __restrict__ colmax_u) {
  __shared__ float cs[128 * 128];  // 64 KiB C-tile staging

  // XCD-chunked bijective swizzle: 8192 blocks = 8 XCDs x 1024
  int bid = blockIdx.x;
  int swz = (bid & 7) * 1024 + (bid >> 3);
  int nt  = swz & 15;   // 16 col tiles (protos)
  int mt  = swz >> 4;   // 512 row tiles (cells)

  int tid  = threadIdx.x;
  int lane = tid & 63;
  int wid  = tid >> 6;
  int wrow = (wid >> 1) * 64;   // cell offset within tile
  int wcol = (wid & 1) * 64;    // proto offset within tile
  int l15  = lane & 15;
  int hi   = lane >> 4;

  // fragment base addresses: row-major bf16, 256 B per row
  const char* Abase = (const char*)zb + ((size_t)(mt * 128 + wrow + l15) * 256 + hi * 16);
  const char* Bbase = (const char*)wb + ((size_t)(nt * 128 + wcol + l15) * 256 + hi * 16);

  f32x4 acc[4][4];
  #pragma unroll
  for (int i = 0; i < 4; ++i)
    #pragma unroll
    for (int j = 0; j < 4; ++j)
      acc[i][j] = f32x4{0.f, 0.f, 0.f, 0.f};

  #pragma unroll
  for (int kk = 0; kk < 4; ++kk) {
    bf16x8 a[4], b[4];
    #pragma unroll
    for (int i = 0; i < 4; ++i) a[i] = *(const bf16x8*)(Abase + i * 4096 + kk * 64);
    #pragma unroll
    for (int j = 0; j < 4; ++j) b[j] = *(const bf16x8*)(Bbase + j * 4096 + kk * 64);
    // SWAPPED: M-operand = protos, N-operand = cells  =>  C/D reg axis = protos
    #pragma unroll
    for (int i = 0; i < 4; ++i)
      #pragma unroll
      for (int j = 0; j < 4; ++j)
        acc[i][j] = __builtin_amdgcn_mfma_f32_16x16x32_bf16(b[j], a[i], acc[i][j], 0, 0, 0);
  }

  // lane (hi,l15), acc[i][j][r]: cell = wrow + i*16 + l15 (local row)
  //                              proto = wcol + j*16 + hi*4 + r (local col)
  size_t growbase = (size_t)mt * 128 + wrow;
  int    gcolbase = nt * 128 + wcol;

  f32x4 wwj[4];
  #pragma unroll
  for (int j = 0; j < 4; ++j)
    wwj[j] = *(const f32x4*)(ww + gcolbase + j * 16 + hi * 4);

  // rowmin(ww - 2L) tracking
  #pragma unroll
  for (int i = 0; i < 4; ++i) {
    size_t row = growbase + (size_t)(i * 16 + l15);
    float vmin = 1e30f;
    #pragma unroll
    for (int j = 0; j < 4; ++j) {
      #pragma unroll
      for (int r = 0; r < 4; ++r) vmin = fminf(vmin, wwj[j][r] - 2.0f * acc[i][j][r]);
    }
    vmin = fminf(vmin, __shfl_xor(vmin, 16, 64));
    vmin = fminf(vmin, __shfl_xor(vmin, 32, 64));
    if (hi == 0) atomicMin(&rowmin_u[row], map_f2u(vmin));
  }

  // colmax(L) per proto: reduce over cells (i regs + l15 lanes)
  #pragma unroll
  for (int j = 0; j < 4; ++j) {
    f32x4 m = acc[0][j];
    #pragma unroll
    for (int i = 1; i < 4; ++i)
      #pragma unroll
      for (int r = 0; r < 4; ++r) m[r] = fmaxf(m[r], acc[i][j][r]);
    #pragma unroll
    for (int s2 = 1; s2 < 16; s2 <<= 1)
      #pragma unroll
      for (int r = 0; r < 4; ++r) m[r] = fmaxf(m[r], __shfl_xor(m[r], s2, 64));
    if (l15 == 0) {
      #pragma unroll
      for (int r = 0; r < 4; ++r)
        atomicMax(&colmax_u[gcolbase + j * 16 + hi * 4 + r], map_f2u(m[r]));
    }
  }

  // stage C tile to LDS; granule-XOR swizzle pg = g ^ ((row&7)<<2)
  #pragma unroll
  for (int i = 0; i < 4; ++i) {
    int row = wrow + i * 16 + l15;
    #pragma unroll
    for (int j = 0; j < 4; ++j) {
      int g  = (wcol >> 2) + j * 4 + hi;
      int pg = g ^ ((row & 7) << 2);
      *(f32x4*)((char*)cs + row * 512 + pg * 16) = acc[i][j];
    }
  }
  __syncthreads();

  // stream out: each wave-instruction writes 2 rows x 512 B contiguous
  {
    int l31  = lane & 31;
    int rsub = lane >> 5;
    #pragma unroll
    for (int it = 0; it < 16; ++it) {
      int row = it * 8 + wid * 2 + rsub;
      int pg  = l31 ^ ((row & 7) << 2);
      f32x4 c = *(const f32x4*)((const char*)cs + row * 512 + pg * 16);
      size_t grow = (size_t)mt * 128 + row;
      *(f32x4*)(logits + grow * K_PROTO + nt * 128 + l31 * 4) = c;
    }
  }
}

// ---- K4: propagation = mean_n sqrt(max(1 + rowmin, 0)) ----
__global__ __launch_bounds__(1024) void prop_k(
    const unsigned int* __restrict__ rowmin_u, float* __restrict__ out) {
  __shared__ float sbuf[16];
  const uint4* p = (const uint4*)rowmin_u;  // 16384 uint4
  float s = 0.f;
  #pragma unroll
  for (int k = 0; k < 16; ++k) {
    uint4 u = p[threadIdx.x + 1024 * k];
    s += sqrtf(fmaxf(1.0f + unmap_u2f(u.x), 0.0f));
    s += sqrtf(fmaxf(1.0f + unmap_u2f(u.y), 0.0f));
    s += sqrtf(fmaxf(1.0f + unmap_u2f(u.z), 0.0f));
    s += sqrtf(fmaxf(1.0f + unmap_u2f(u.w), 0.0f));
  }
  #pragma unroll
  for (int off = 1; off < 64; off <<= 1) s += __shfl_xor(s, off, 64);
  int wid = threadIdx.x >> 6, lane = threadIdx.x & 63;
  if (lane == 0) sbuf[wid] = s;
  __syncthreads();
  if (threadIdx.x == 0) {
    float t = 0.f;
    #pragma unroll
    for (int w = 0; w < 16; ++w) t += sbuf[w];
    out[0] = t * (1.0f / N_CELLS);
  }
}

// ---- K5: emb_similarity = mean_k sqrt(max(1 + ww[k] - 2*colmax[k], 0)) ----
__global__ __launch_bounds__(1024) void emb_k(
    const unsigned int* __restrict__ colmax_u, const float* __restrict__ ww,
    float* __restrict__ out) {
  __shared__ float sbuf[16];
  float s = 0.f;
  for (int idx = threadIdx.x; idx < K_PROTO; idx += 1024)
    s += sqrtf(fmaxf(1.0f + ww[idx] - 2.0f * unmap_u2f(colmax_u[idx]), 0.0f));
  #pragma unroll
  for (int off = 1; off < 64; off <<= 1) s += __shfl_xor(s, off, 64);
  int wid = threadIdx.x >> 6, lane = threadIdx.x & 63;
  if (lane == 0) sbuf[wid] = s;
  __syncthreads();
  if (threadIdx.x == 0) {
    float t = 0.f;
    #pragma unroll
    for (int w = 0; w < 16; ++w) t += sbuf[w];
    out[0] = t * (1.0f / K_PROTO);
  }
}

extern "C" void kernel_launch(void* const* d_in, const int* in_sizes, int n_in,
                              void* d_out, int out_size, void* d_ws, size_t ws_size,
                              hipStream_t stream) {
  const float* x     = (const float*)d_in[0];
  const float* W     = (const float*)d_in[1];
  const float* recon = (const float*)d_in[2];
  const float* kl    = (const float*)d_in[3];
  const float* mmd   = (const float*)d_in[4];

  float* out    = (float*)d_out;
  float* z      = out;
  float* logits = out + (size_t)N_CELLS * D_DIM;
  float* scal   = logits + (size_t)N_CELLS * K_PROTO;  // [cvae, prop, emb]

  char* ws = (char*)d_ws;
  unsigned int* zb = (unsigned int*)ws;                     // 16 MiB packed bf16
  size_t off = (size_t)N_CELLS * D_DIM * 2;
  unsigned int* wb = (unsigned int*)(ws + off);             // 0.5 MiB
  off += (size_t)K_PROTO * D_DIM * 2;
  float* ww = (float*)(ws + off);                           // 8 KiB
  off += (size_t)K_PROTO * 4;
  unsigned int* rowmin_u = (unsigned int*)(ws + off);       // 256 KiB
  off += (size_t)N_CELLS * 4;
  unsigned int* colmax_u = (unsigned int*)(ws + off);       // 8 KiB

  normalize_k<<<N_CELLS / 8, 256, 0, stream>>>(x, z, zb, rowmin_u);
  wprep_k<<<K_PROTO / 8, 256, 0, stream>>>(W, wb, ww, colmax_u, recon, kl, mmd, scal);
  gemm_k<<<(N_CELLS / 128) * (K_PROTO / 128), 256, 0, stream>>>(
      (const unsigned short*)zb, (const unsigned short*)wb, ww, logits,
      rowmin_u, colmax_u);
  prop_k<<<1, 1024, 0, stream>>>(rowmin_u, scal + 1);
  emb_k<<<1, 1024, 0, stream>>>(colmax_u, ww, scal + 2);
}

// Round 7
// 206.373 us; speedup vs baseline: 1.2195x; 1.1775x over previous
//
#include <hip/hip_runtime.h>
#include <hip/hip_bf16.h>
#include <math.h>

#define N_CELLS 65536
#define D_DIM   128
#define K_PROTO 2048

typedef __attribute__((ext_vector_type(8))) short bf16x8;
typedef __attribute__((ext_vector_type(4))) float f32x4;

// ---- order-preserving float<->uint mapping for atomic min/max ----
__device__ __forceinline__ unsigned int map_f2u(float f) {
  unsigned int u = __float_as_uint(f);
  return (u & 0x80000000u) ? ~u : (u | 0x80000000u);
}
__device__ __forceinline__ float unmap_u2f(unsigned int u) {
  unsigned int b = (u & 0x80000000u) ? (u ^ 0x80000000u) : ~u;
  return __uint_as_float(b);
}

// RTN-even float -> bf16 bit pattern
__device__ __forceinline__ unsigned int f2bf(float f) {
  unsigned int u = __float_as_uint(f);
  return ((u + 0x7FFFu + ((u >> 16) & 1u)) >> 16) & 0xFFFFu;
}

// ---- K1: row-normalize x -> z (NT float4 out) + zb (packed bf16) + rowmin init ----
__global__ __launch_bounds__(256) void normalize_k(
    const float* __restrict__ x, float* __restrict__ z,
    unsigned int* __restrict__ zb, unsigned int* __restrict__ rowmin_u) {
  int tid = threadIdx.x;
  int sub = tid & 31;                       // lane within half-wave = col group
  int row = blockIdx.x * 8 + (tid >> 5);    // one row per 32 lanes
  const f32x4* xr = (const f32x4*)(x + (size_t)row * D_DIM);
  f32x4 v = xr[sub];
  float s = v.x * v.x + v.y * v.y + v.z * v.z + v.w * v.w;
  #pragma unroll
  for (int off = 1; off < 32; off <<= 1) s += __shfl_xor(s, off, 64);
  float inv = 1.0f / fmaxf(sqrtf(s), 1e-12f);
  f32x4 zv = v * inv;
  __builtin_nontemporal_store(zv, (f32x4*)(z + (size_t)row * D_DIM) + sub);
  unsigned int lo = (f2bf(zv.y) << 16) | f2bf(zv.x);
  unsigned int h2 = (f2bf(zv.w) << 16) | f2bf(zv.z);
  unsigned long long pk = ((unsigned long long)h2 << 32) | lo;
  *((unsigned long long*)(zb + (size_t)row * (D_DIM / 2)) + sub) = pk;
  if (sub == 0) rowmin_u[row] = 0xFFFFFFFFu;  // min identity (mapped order)
}

// ---- K2: W -> bf16 + ww norms + colmax init; block 0 writes cvae ----
__global__ __launch_bounds__(256) void wprep_k(
    const float* __restrict__ W, unsigned int* __restrict__ wb,
    float* __restrict__ ww, unsigned int* __restrict__ colmax_u,
    const float* __restrict__ recon, const float* __restrict__ kl,
    const float* __restrict__ mmd, float* __restrict__ scal) {
  if (blockIdx.x == 0 && threadIdx.x == 0) {
    scal[0] = recon[0] + 0.5f * kl[0] + mmd[0];  // cvae_loss
  }
  int tid = threadIdx.x;
  int sub = tid & 31;
  int row = blockIdx.x * 8 + (tid >> 5);
  const f32x4* wr = (const f32x4*)(W + (size_t)row * D_DIM);
  f32x4 v = wr[sub];
  float s = v.x * v.x + v.y * v.y + v.z * v.z + v.w * v.w;
  #pragma unroll
  for (int off = 1; off < 32; off <<= 1) s += __shfl_xor(s, off, 64);
  if (sub == 0) {
    ww[row] = s;
    colmax_u[row] = 0u;  // max identity (mapped order)
  }
  unsigned int lo = (f2bf(v.y) << 16) | f2bf(v.x);
  unsigned int h2 = (f2bf(v.w) << 16) | f2bf(v.z);
  unsigned long long pk = ((unsigned long long)h2 << 32) | lo;
  *((unsigned long long*)(wb + (size_t)row * (D_DIM / 2)) + sub) = pk;
}

// ---- K3: LDS-free mainloop GEMM + LDS-transposed NT contiguous store epilogue ----
__global__ __launch_bounds__(256) void gemm_k(
    const unsigned short* __restrict__ zb, const unsigned short* __restrict__ wb,
    const float* __restrict__ ww, float* __restrict__ logits,
    unsigned int* __restrict__ rowmin_u, unsigned int* __restrict__ colmax_u) {
  __shared__ float cs[128 * 128];  // 64 KiB C-tile staging

  // XCD-chunked bijective swizzle: 8192 blocks = 8 XCDs x 1024
  int bid = blockIdx.x;
  int swz = (bid & 7) * 1024 + (bid >> 3);
  int nt  = swz & 15;   // 16 col tiles (protos)
  int mt  = swz >> 4;   // 512 row tiles (cells)

  int tid  = threadIdx.x;
  int lane = tid & 63;
  int wid  = tid >> 6;
  int wrow = (wid >> 1) * 64;   // cell offset within tile
  int wcol = (wid & 1) * 64;    // proto offset within tile
  int l15  = lane & 15;
  int hi   = lane >> 4;

  // fragment base addresses: row-major bf16, 256 B per row
  const char* Abase = (const char*)zb + ((size_t)(mt * 128 + wrow + l15) * 256 + hi * 16);
  const char* Bbase = (const char*)wb + ((size_t)(nt * 128 + wcol + l15) * 256 + hi * 16);

  f32x4 acc[4][4];
  #pragma unroll
  for (int i = 0; i < 4; ++i)
    #pragma unroll
    for (int j = 0; j < 4; ++j)
      acc[i][j] = f32x4{0.f, 0.f, 0.f, 0.f};

  #pragma unroll
  for (int kk = 0; kk < 4; ++kk) {
    bf16x8 a[4], b[4];
    #pragma unroll
    for (int i = 0; i < 4; ++i) a[i] = *(const bf16x8*)(Abase + i * 4096 + kk * 64);
    #pragma unroll
    for (int j = 0; j < 4; ++j) b[j] = *(const bf16x8*)(Bbase + j * 4096 + kk * 64);
    // SWAPPED: M-operand = protos, N-operand = cells  =>  C/D reg axis = protos
    #pragma unroll
    for (int i = 0; i < 4; ++i)
      #pragma unroll
      for (int j = 0; j < 4; ++j)
        acc[i][j] = __builtin_amdgcn_mfma_f32_16x16x32_bf16(b[j], a[i], acc[i][j], 0, 0, 0);
  }

  // lane (hi,l15), acc[i][j][r]: cell = wrow + i*16 + l15 (local row)
  //                              proto = wcol + j*16 + hi*4 + r (local col)
  size_t growbase = (size_t)mt * 128 + wrow;
  int    gcolbase = nt * 128 + wcol;

  f32x4 wwj[4];
  #pragma unroll
  for (int j = 0; j < 4; ++j)
    wwj[j] = *(const f32x4*)(ww + gcolbase + j * 16 + hi * 4);

  // rowmin(ww - 2L) tracking
  #pragma unroll
  for (int i = 0; i < 4; ++i) {
    size_t row = growbase + (size_t)(i * 16 + l15);
    float vmin = 1e30f;
    #pragma unroll
    for (int j = 0; j < 4; ++j) {
      #pragma unroll
      for (int r = 0; r < 4; ++r) vmin = fminf(vmin, wwj[j][r] - 2.0f * acc[i][j][r]);
    }
    vmin = fminf(vmin, __shfl_xor(vmin, 16, 64));
    vmin = fminf(vmin, __shfl_xor(vmin, 32, 64));
    if (hi == 0) atomicMin(&rowmin_u[row], map_f2u(vmin));
  }

  // colmax(L) per proto: reduce over cells (i regs + l15 lanes)
  #pragma unroll
  for (int j = 0; j < 4; ++j) {
    f32x4 m = acc[0][j];
    #pragma unroll
    for (int i = 1; i < 4; ++i)
      #pragma unroll
      for (int r = 0; r < 4; ++r) m[r] = fmaxf(m[r], acc[i][j][r]);
    #pragma unroll
    for (int s2 = 1; s2 < 16; s2 <<= 1)
      #pragma unroll
      for (int r = 0; r < 4; ++r) m[r] = fmaxf(m[r], __shfl_xor(m[r], s2, 64));
    if (l15 == 0) {
      #pragma unroll
      for (int r = 0; r < 4; ++r)
        atomicMax(&colmax_u[gcolbase + j * 16 + hi * 4 + r], map_f2u(m[r]));
    }
  }

  // stage C tile to LDS; granule-XOR swizzle pg = g ^ ((row&7)<<2)
  #pragma unroll
  for (int i = 0; i < 4; ++i) {
    int row = wrow + i * 16 + l15;
    #pragma unroll
    for (int j = 0; j < 4; ++j) {
      int g  = (wcol >> 2) + j * 4 + hi;
      int pg = g ^ ((row & 7) << 2);
      *(f32x4*)((char*)cs + row * 512 + pg * 16) = acc[i][j];
    }
  }
  __syncthreads();

  // stream out: each wave-instruction writes 2 rows x 512 B contiguous, NT
  {
    int l31  = lane & 31;
    int rsub = lane >> 5;
    #pragma unroll
    for (int it = 0; it < 16; ++it) {
      int row = it * 8 + wid * 2 + rsub;
      int pg  = l31 ^ ((row & 7) << 2);
      f32x4 c = *(const f32x4*)((const char*)cs + row * 512 + pg * 16);
      size_t grow = (size_t)mt * 128 + row;
      __builtin_nontemporal_store(c, (f32x4*)(logits + grow * K_PROTO + nt * 128 + l31 * 4));
    }
  }
}

// ---- K4: propagation = mean_n sqrt(max(1 + rowmin, 0)) ----
__global__ __launch_bounds__(1024) void prop_k(
    const unsigned int* __restrict__ rowmin_u, float* __restrict__ out) {
  __shared__ float sbuf[16];
  const uint4* p = (const uint4*)rowmin_u;  // 16384 uint4
  float s = 0.f;
  #pragma unroll
  for (int k = 0; k < 16; ++k) {
    uint4 u = p[threadIdx.x + 1024 * k];
    s += sqrtf(fmaxf(1.0f + unmap_u2f(u.x), 0.0f));
    s += sqrtf(fmaxf(1.0f + unmap_u2f(u.y), 0.0f));
    s += sqrtf(fmaxf(1.0f + unmap_u2f(u.z), 0.0f));
    s += sqrtf(fmaxf(1.0f + unmap_u2f(u.w), 0.0f));
  }
  #pragma unroll
  for (int off = 1; off < 64; off <<= 1) s += __shfl_xor(s, off, 64);
  int wid = threadIdx.x >> 6, lane = threadIdx.x & 63;
  if (lane == 0) sbuf[wid] = s;
  __syncthreads();
  if (threadIdx.x == 0) {
    float t = 0.f;
    #pragma unroll
    for (int w = 0; w < 16; ++w) t += sbuf[w];
    out[0] = t * (1.0f / N_CELLS);
  }
}

// ---- K5: emb_similarity = mean_k sqrt(max(1 + ww[k] - 2*colmax[k], 0)) ----
__global__ __launch_bounds__(1024) void emb_k(
    const unsigned int* __restrict__ colmax_u, const float* __restrict__ ww,
    float* __restrict__ out) {
  __shared__ float sbuf[16];
  float s = 0.f;
  for (int idx = threadIdx.x; idx < K_PROTO; idx += 1024)
    s += sqrtf(fmaxf(1.0f + ww[idx] - 2.0f * unmap_u2f(colmax_u[idx]), 0.0f));
  #pragma unroll
  for (int off = 1; off < 64; off <<= 1) s += __shfl_xor(s, off, 64);
  int wid = threadIdx.x >> 6, lane = threadIdx.x & 63;
  if (lane == 0) sbuf[wid] = s;
  __syncthreads();
  if (threadIdx.x == 0) {
    float t = 0.f;
    #pragma unroll
    for (int w = 0; w < 16; ++w) t += sbuf[w];
    out[0] = t * (1.0f / K_PROTO);
  }
}

extern "C" void kernel_launch(void* const* d_in, const int* in_sizes, int n_in,
                              void* d_out, int out_size, void* d_ws, size_t ws_size,
                              hipStream_t stream) {
  const float* x     = (const float*)d_in[0];
  const float* W     = (const float*)d_in[1];
  const float* recon = (const float*)d_in[2];
  const float* kl    = (const float*)d_in[3];
  const float* mmd   = (const float*)d_in[4];

  float* out    = (float*)d_out;
  float* z      = out;
  float* logits = out + (size_t)N_CELLS * D_DIM;
  float* scal   = logits + (size_t)N_CELLS * K_PROTO;  // [cvae, prop, emb]

  char* ws = (char*)d_ws;
  unsigned int* zb = (unsigned int*)ws;                     // 16 MiB packed bf16
  size_t off = (size_t)N_CELLS * D_DIM * 2;
  unsigned int* wb = (unsigned int*)(ws + off);             // 0.5 MiB
  off += (size_t)K_PROTO * D_DIM * 2;
  float* ww = (float*)(ws + off);                           // 8 KiB
  off += (size_t)K_PROTO * 4;
  unsigned int* rowmin_u = (unsigned int*)(ws + off);       // 256 KiB
  off += (size_t)N_CELLS * 4;
  unsigned int* colmax_u = (unsigned int*)(ws + off);       // 8 KiB

  normalize_k<<<N_CELLS / 8, 256, 0, stream>>>(x, z, zb, rowmin_u);
  wprep_k<<<K_PROTO / 8, 256, 0, stream>>>(W, wb, ww, colmax_u, recon, kl, mmd, scal);
  gemm_k<<<(N_CELLS / 128) * (K_PROTO / 128), 256, 0, stream>>>(
      (const unsigned short*)zb, (const unsigned short*)wb, ww, logits,
      rowmin_u, colmax_u);
  prop_k<<<1, 1024, 0, stream>>>(rowmin_u, scal + 1);
  emb_k<<<1, 1024, 0, stream>>>(colmax_u, ww, scal + 2);
}

// Round 9
// 191.770 us; speedup vs baseline: 1.3124x; 1.0762x over previous
//
#include <hip/hip_runtime.h>
#include <hip/hip_bf16.h>
#include <math.h>

#define N_CELLS 65536
#define D_DIM   128
#define K_PROTO 2048

typedef __attribute__((ext_vector_type(8))) short bf16x8;
typedef __attribute__((ext_vector_type(4))) float f32x4;

// RTN-even float -> bf16 bit pattern
__device__ __forceinline__ unsigned int f2bf(float f) {
  unsigned int u = __float_as_uint(f);
  return ((u + 0x7FFFu + ((u >> 16) & 1u)) >> 16) & 0xFFFFu;
}

// ---- K1: row-normalize x -> z (NT float4 out) + zb (packed bf16) ----
__global__ __launch_bounds__(256) void normalize_k(
    const float* __restrict__ x, float* __restrict__ z,
    unsigned int* __restrict__ zb) {
  int tid = threadIdx.x;
  int sub = tid & 31;
  int row = blockIdx.x * 8 + (tid >> 5);
  const f32x4* xr = (const f32x4*)(x + (size_t)row * D_DIM);
  f32x4 v = xr[sub];
  float s = v.x * v.x + v.y * v.y + v.z * v.z + v.w * v.w;
  #pragma unroll
  for (int off = 1; off < 32; off <<= 1) s += __shfl_xor(s, off, 64);
  float inv = 1.0f / fmaxf(sqrtf(s), 1e-12f);
  f32x4 zv = v * inv;
  __builtin_nontemporal_store(zv, (f32x4*)(z + (size_t)row * D_DIM) + sub);
  unsigned int lo = (f2bf(zv.y) << 16) | f2bf(zv.x);
  unsigned int h2 = (f2bf(zv.w) << 16) | f2bf(zv.z);
  unsigned long long pk = ((unsigned long long)h2 << 32) | lo;
  *((unsigned long long*)(zb + (size_t)row * (D_DIM / 2)) + sub) = pk;
}

// ---- K2: W -> bf16 + ww norms; block 0 writes cvae ----
__global__ __launch_bounds__(256) void wprep_k(
    const float* __restrict__ W, unsigned int* __restrict__ wb,
    float* __restrict__ ww,
    const float* __restrict__ recon, const float* __restrict__ kl,
    const float* __restrict__ mmd, float* __restrict__ scal) {
  if (blockIdx.x == 0 && threadIdx.x == 0) {
    scal[0] = recon[0] + 0.5f * kl[0] + mmd[0];  // cvae_loss
  }
  int tid = threadIdx.x;
  int sub = tid & 31;
  int row = blockIdx.x * 8 + (tid >> 5);
  const f32x4* wr = (const f32x4*)(W + (size_t)row * D_DIM);
  f32x4 v = wr[sub];
  float s = v.x * v.x + v.y * v.y + v.z * v.z + v.w * v.w;
  #pragma unroll
  for (int off = 1; off < 32; off <<= 1) s += __shfl_xor(s, off, 64);
  if (sub == 0) ww[row] = s;
  unsigned int lo = (f2bf(v.y) << 16) | f2bf(v.x);
  unsigned int h2 = (f2bf(v.w) << 16) | f2bf(v.z);
  unsigned long long pk = ((unsigned long long)h2 << 32) | lo;
  *((unsigned long long*)(wb + (size_t)row * (D_DIM / 2)) + sub) = pk;
}

// ---- K3: GEMM + NT contiguous stores + atomic-free min/max partials ----
__global__ __launch_bounds__(256) void gemm_k(
    const unsigned short* __restrict__ zb, const unsigned short* __restrict__ wb,
    const float* __restrict__ ww, float* __restrict__ logits,
    float* __restrict__ rowmin_part, float* __restrict__ colmax_part) {
  __shared__ float cs[128 * 128];   // 64 KiB C-tile staging
  __shared__ float rmin[2][128];    // per-colhalf row mins
  __shared__ float cmx[2][128];     // per-rowhalf col maxes

  int bid = blockIdx.x;
  int swz = (bid & 7) * 1024 + (bid >> 3);
  int nt  = swz & 15;
  int mt  = swz >> 4;

  int tid  = threadIdx.x;
  int lane = tid & 63;
  int wid  = tid >> 6;
  int wrow = (wid >> 1) * 64;
  int wcol = (wid & 1) * 64;
  int l15  = lane & 15;
  int hi   = lane >> 4;

  const char* Abase = (const char*)zb + ((size_t)(mt * 128 + wrow + l15) * 256 + hi * 16);
  const char* Bbase = (const char*)wb + ((size_t)(nt * 128 + wcol + l15) * 256 + hi * 16);

  f32x4 acc[4][4];
  #pragma unroll
  for (int i = 0; i < 4; ++i)
    #pragma unroll
    for (int j = 0; j < 4; ++j)
      acc[i][j] = f32x4{0.f, 0.f, 0.f, 0.f};

  #pragma unroll
  for (int kk = 0; kk < 4; ++kk) {
    bf16x8 a[4], b[4];
    #pragma unroll
    for (int i = 0; i < 4; ++i) a[i] = *(const bf16x8*)(Abase + i * 4096 + kk * 64);
    #pragma unroll
    for (int j = 0; j < 4; ++j) b[j] = *(const bf16x8*)(Bbase + j * 4096 + kk * 64);
    // SWAPPED: C/D reg axis = protos
    #pragma unroll
    for (int i = 0; i < 4; ++i)
      #pragma unroll
      for (int j = 0; j < 4; ++j)
        acc[i][j] = __builtin_amdgcn_mfma_f32_16x16x32_bf16(b[j], a[i], acc[i][j], 0, 0, 0);
  }

  int gcolbase = nt * 128 + wcol;
  f32x4 wwj[4];
  #pragma unroll
  for (int j = 0; j < 4; ++j)
    wwj[j] = *(const f32x4*)(ww + gcolbase + j * 16 + hi * 4);

  // per-wave rowmin(ww - 2L): lane (hi,l15) covers row wrow+i*16+l15
  #pragma unroll
  for (int i = 0; i < 4; ++i) {
    float vmin = 1e30f;
    #pragma unroll
    for (int j = 0; j < 4; ++j)
      #pragma unroll
      for (int r = 0; r < 4; ++r) vmin = fminf(vmin, wwj[j][r] - 2.0f * acc[i][j][r]);
    vmin = fminf(vmin, __shfl_xor(vmin, 16, 64));
    vmin = fminf(vmin, __shfl_xor(vmin, 32, 64));
    if (hi == 0) rmin[wid & 1][wrow + i * 16 + l15] = vmin;
  }

  // per-wave colmax(L): reduce over i regs + l15 lanes
  #pragma unroll
  for (int j = 0; j < 4; ++j) {
    f32x4 m = acc[0][j];
    #pragma unroll
    for (int i = 1; i < 4; ++i)
      #pragma unroll
      for (int r = 0; r < 4; ++r) m[r] = fmaxf(m[r], acc[i][j][r]);
    #pragma unroll
    for (int s2 = 1; s2 < 16; s2 <<= 1)
      #pragma unroll
      for (int r = 0; r < 4; ++r) m[r] = fmaxf(m[r], __shfl_xor(m[r], s2, 64));
    if (l15 == 0)
      *(f32x4*)&cmx[wid >> 1][wcol + j * 16 + hi * 4] = m;
  }

  // stage C tile to LDS; granule-XOR swizzle
  #pragma unroll
  for (int i = 0; i < 4; ++i) {
    int row = wrow + i * 16 + l15;
    #pragma unroll
    for (int j = 0; j < 4; ++j) {
      int g  = (wcol >> 2) + j * 4 + hi;
      int pg = g ^ ((row & 7) << 2);
      *(f32x4*)((char*)cs + row * 512 + pg * 16) = acc[i][j];
    }
  }
  __syncthreads();

  // combined partials (one write per row/col per block, no atomics)
  if (tid < 128) {
    rowmin_part[(size_t)nt * N_CELLS + mt * 128 + tid] =
        fminf(rmin[0][tid], rmin[1][tid]);
  } else {
    int c = tid - 128;
    colmax_part[(size_t)mt * K_PROTO + nt * 128 + c] =
        fmaxf(cmx[0][c], cmx[1][c]);
  }

  // stream out: 2 rows x 512 B contiguous per wave-instruction, NT
  {
    int l31  = lane & 31;
    int rsub = lane >> 5;
    #pragma unroll
    for (int it = 0; it < 16; ++it) {
      int row = it * 8 + wid * 2 + rsub;
      int pg  = l31 ^ ((row & 7) << 2);
      f32x4 c = *(const f32x4*)((const char*)cs + row * 512 + pg * 16);
      size_t grow = (size_t)mt * 128 + row;
      __builtin_nontemporal_store(c, (f32x4*)(logits + grow * K_PROTO + nt * 128 + l31 * 4));
    }
  }
}

// ---- K4: rowmin over 16 nt-planes -> sqrt -> per-block sum ----
__global__ __launch_bounds__(1024) void prop1_k(
    const float* __restrict__ rowmin_part, float* __restrict__ prop_part) {
  __shared__ float sbuf[16];
  int slot = blockIdx.x * 1024 + threadIdx.x;   // 16384 float4 slots
  f32x4 v = *(const f32x4*)(rowmin_part + (size_t)slot * 4);
  #pragma unroll
  for (int p = 1; p < 16; ++p) {
    f32x4 u = *(const f32x4*)(rowmin_part + (size_t)p * N_CELLS + (size_t)slot * 4);
    #pragma unroll
    for (int r = 0; r < 4; ++r) v[r] = fminf(v[r], u[r]);
  }
  float s = 0.f;
  #pragma unroll
  for (int r = 0; r < 4; ++r) s += sqrtf(fmaxf(1.0f + v[r], 0.0f));
  #pragma unroll
  for (int off = 1; off < 64; off <<= 1) s += __shfl_xor(s, off, 64);
  int wv = threadIdx.x >> 6, lane = threadIdx.x & 63;
  if (lane == 0) sbuf[wv] = s;
  __syncthreads();
  if (threadIdx.x == 0) {
    float t = 0.f;
    #pragma unroll
    for (int w = 0; w < 16; ++w) t += sbuf[w];
    prop_part[blockIdx.x] = t;
  }
}

// ---- K5: colmax over 512 mt-planes -> sqrt(1+ww-2max) -> per-block sum ----
__global__ __launch_bounds__(1024) void emb1_k(
    const float* __restrict__ colmax_part, const float* __restrict__ ww,
    float* __restrict__ emb_part) {
  __shared__ float buf[8][128];
  __shared__ float sbuf[2];
  int t   = threadIdx.x;
  int col = blockIdx.x * 128 + (t & 127);
  int seg = t >> 7;                      // 0..7, 64 mt each
  float m = -1e30f;
  for (int k = 0; k < 64; ++k)
    m = fmaxf(m, colmax_part[(size_t)(seg * 64 + k) * K_PROTO + col]);
  buf[seg][t & 127] = m;
  __syncthreads();
  if (t < 128) {
    float tot = buf[0][t];
    #pragma unroll
    for (int s2 = 1; s2 < 8; ++s2) tot = fmaxf(tot, buf[s2][t]);
    float val = sqrtf(fmaxf(1.0f + ww[col] - 2.0f * tot, 0.0f));
    #pragma unroll
    for (int off = 1; off < 64; off <<= 1) val += __shfl_xor(val, off, 64);
    if ((t & 63) == 0) sbuf[t >> 6] = val;
  }
  __syncthreads();
  if (t == 0) emb_part[blockIdx.x] = sbuf[0] + sbuf[1];
}

// ---- K6: final scalars ----
__global__ __launch_bounds__(64) void final_k(
    const float* __restrict__ prop_part, const float* __restrict__ emb_part,
    float* __restrict__ scal) {
  if (threadIdx.x == 0) {
    float p = 0.f, e = 0.f;
    #pragma unroll
    for (int i = 0; i < 16; ++i) { p += prop_part[i]; e += emb_part[i]; }
    scal[1] = p * (1.0f / N_CELLS);
    scal[2] = e * (1.0f / K_PROTO);
  }
}

extern "C" void kernel_launch(void* const* d_in, const int* in_sizes, int n_in,
                              void* d_out, int out_size, void* d_ws, size_t ws_size,
                              hipStream_t stream) {
  const float* x     = (const float*)d_in[0];
  const float* W     = (const float*)d_in[1];
  const float* recon = (const float*)d_in[2];
  const float* kl    = (const float*)d_in[3];
  const float* mmd   = (const float*)d_in[4];

  float* out    = (float*)d_out;
  float* z      = out;
  float* logits = out + (size_t)N_CELLS * D_DIM;
  float* scal   = logits + (size_t)N_CELLS * K_PROTO;  // [cvae, prop, emb]

  char* ws = (char*)d_ws;
  unsigned int* zb = (unsigned int*)ws;                     // 16 MiB packed bf16
  size_t off = (size_t)N_CELLS * D_DIM * 2;
  unsigned int* wb = (unsigned int*)(ws + off);             // 0.5 MiB
  off += (size_t)K_PROTO * D_DIM * 2;
  float* ww = (float*)(ws + off);                           // 8 KiB
  off += (size_t)K_PROTO * 4;
  float* rowmin_part = (float*)(ws + off);                  // 16 x 65536 f32 = 4 MiB
  off += (size_t)16 * N_CELLS * 4;
  float* colmax_part = (float*)(ws + off);                  // 512 x 2048 f32 = 4 MiB
  off += (size_t)512 * K_PROTO * 4;
  float* prop_part = (float*)(ws + off);                    // 16 f32
  off += 16 * 4;
  float* emb_part = (float*)(ws + off);                     // 16 f32

  normalize_k<<<N_CELLS / 8, 256, 0, stream>>>(x, z, zb);
  wprep_k<<<K_PROTO / 8, 256, 0, stream>>>(W, wb, ww, recon, kl, mmd, scal);
  gemm_k<<<(N_CELLS / 128) * (K_PROTO / 128), 256, 0, stream>>>(
      (const unsigned short*)zb, (const unsigned short*)wb, ww, logits,
      rowmin_part, colmax_part);
  prop1_k<<<16, 1024, 0, stream>>>(rowmin_part, prop_part);
  emb1_k<<<16, 1024, 0, stream>>>(colmax_part, ww, emb_part);
  final_k<<<1, 64, 0, stream>>>(prop_part, emb_part, scal);
}